// Round 7
// baseline (371.296 us; speedup 1.0000x reference)
//
#include <hip/hip_runtime.h>
#include <hip/hip_bf16.h>

// ReLU-LSTM fused, round 7: precast f32->bf16 (pre-swizzled) into d_ws, then
// round-2's validated 2-barrier GEMM skeleton with A read direct from global
// (wave-private registers, L2-resident via XCD-grouped block swizzle) and only
// B staged in LDS (32 KB). 4-gate shared-A accumulation + in-register LSTM
// epilogue.

#define HID 2048
#define BATCH_N 4096
#define KTOT 4096
#define BK 64
#define THREADS 256

typedef __attribute__((ext_vector_type(4))) float f32x4;
typedef __attribute__((ext_vector_type(8))) short bf16x8;

__device__ __forceinline__ short f2bf(float f) {
    union { float f; unsigned u; } v; v.f = f;
    unsigned r = v.u + 0x7FFFu + ((v.u >> 16) & 1u);
    return (short)(r >> 16);
}

__device__ __forceinline__ float fast_tanh(float v) {
    float e = __expf(2.0f * v);
    return 1.0f - 2.0f / (e + 1.0f);
}

__device__ __forceinline__ void gload_lds16(const short* g, short* l) {
    __builtin_amdgcn_global_load_lds(
        (const __attribute__((address_space(1))) unsigned int*)g,
        (__attribute__((address_space(3))) unsigned int*)l, 16, 0, 0);
}

// ---------------------------------------------------------------------------
// Kernel 1: precast f32 -> bf16 with within-64 K-swizzle keyed on (row&7).
// Stored col = (k & ~63) | ((k&63) ^ ((row&7)<<3)); the LDS path (linear
// global_load_lds dest) and the A-direct register path both read with the
// same XOR, so the involution matches on both sides (rule 21).
// ---------------------------------------------------------------------------
struct CastParams {
    const float* x; const float* h;
    const float* Wx[4]; const float* Wh[4];
    short* A; short* B;
};

__global__ __launch_bounds__(256) void precast_kernel(CastParams q) {
    const long A_CH = (long)BATCH_N * (KTOT / 8);   // 2^21 16B-chunks
    const long B_CH = 4L * HID * (KTOT / 8);        // 2^22
    const long total = A_CH + B_CH;
    for (long idx = (long)blockIdx.x * 256 + threadIdx.x; idx < total;
         idx += (long)gridDim.x * 256) {
        const float* src; short* dst; int row, k;
        if (idx < A_CH) {
            row = (int)(idx >> 9);
            k = (int)(idx & 511) << 3;
            src = (k < HID) ? &q.x[(size_t)row * HID + k]
                            : &q.h[(size_t)row * HID + (k - HID)];
            dst = &q.A[(size_t)row * KTOT];
        } else {
            long r = idx - A_CH;
            int g = (int)(r >> 20);
            int rem = (int)(r & ((1 << 20) - 1));
            row = rem >> 9;
            k = (rem & 511) << 3;
            src = (k < HID) ? &q.Wx[g][(size_t)row * HID + k]
                            : &q.Wh[g][(size_t)row * HID + (k - HID)];
            dst = &q.B[((size_t)g * HID + row) * KTOT];
        }
        float4 v0 = *(const float4*)src;
        float4 v1 = *(const float4*)(src + 4);
        int col = (k & ~63) | ((k & 63) ^ ((row & 7) << 3));
        bf16x8 s;
        s[0] = f2bf(v0.x); s[1] = f2bf(v0.y); s[2] = f2bf(v0.z); s[3] = f2bf(v0.w);
        s[4] = f2bf(v1.x); s[5] = f2bf(v1.y); s[6] = f2bf(v1.z); s[7] = f2bf(v1.w);
        *(bf16x8*)&dst[col] = s;
    }
}

// ---------------------------------------------------------------------------
// Kernel 2: A-direct GEMM + LSTM, round-2 sync skeleton.
// Block = 128 rows x 64 cols x 4 gates, 256 threads = 4 waves (2M x 2N).
//   - A fragments: global b128 loads into registers, issued with the B stage
//     before the barrier (the barrier's vmcnt(0) drain covers both).
//   - B: single 32 KB LDS buffer via global_load_lds (exact round-2 pattern:
//     STAGE; bar; COMPUTE; bar — all LDS hazards barrier-bracketed).
//   - New hazards are register RAW only (compiler-precise; cannot race).
// ---------------------------------------------------------------------------
struct GemmParams {
    const short* A; const short* B;
    const float* bx[4];
    const float* c;
    float* oh; float* oc;
};

__global__ __launch_bounds__(THREADS, 2) void gemm_lstm_adir2(GemmParams p) {
    __shared__ short sB[4 * 4096];       // [gate][64 rows][64 k] = 32 KB

    const int t = threadIdx.x;
    const int wave = t >> 6;
    const int lane = t & 63;
    const int wm = (wave >> 1) * 64;
    const int wn = (wave & 1) * 32;
    const int lr = lane & 15;
    const int lk = (lane >> 4) * 8;
    const int sw = (lane & 7) << 3;      // (row&7)<<3; rows ≡ lr (mod 8)
    const int koff0 = lk ^ sw;
    const int koff1 = (32 + lk) ^ sw;

    // XCD-grouped swizzle: 1024 blocks = 8 XCD x 128; each XCD's contiguous
    // nb-range spans few bm-panels -> A panels L2-resident per XCD.
    const int b0 = blockIdx.x;
    const int nb = (b0 & 7) * 128 + (b0 >> 3);
    const int bm = (nb >> 5) * 128;
    const int bn = (nb & 31) * 64;

    // A-direct per-lane element offsets (loop-invariant; + k0 per tile)
    int voffA[4][2];
    #pragma unroll
    for (int m = 0; m < 4; ++m) {
        int row = bm + wm + m * 16 + lr;
        voffA[m][0] = row * KTOT + koff0;
        voffA[m][1] = row * KTOT + koff1;
    }

    // B staging: wave w stages gate w; 8 calls x (8 rows x 64 k) each.
    const int srow = lane >> 3;
    const int kch = (lane & 7) * 8;
    const short* gB = p.B + ((size_t)wave * HID + bn + srow) * KTOT + kch;

    f32x4 acc[4][4][2];
    #pragma unroll
    for (int g = 0; g < 4; ++g)
        #pragma unroll
        for (int m = 0; m < 4; ++m)
            #pragma unroll
            for (int n = 0; n < 2; ++n)
                acc[g][m][n] = (f32x4){0.f, 0.f, 0.f, 0.f};

    bf16x8 a[4][2];

    for (int k0 = 0; k0 < KTOT; k0 += BK) {
        // ---- stage B(k0) -> LDS, load A(k0) -> regs (all before barrier) ----
        #pragma unroll
        for (int j = 0; j < 8; ++j)
            gload_lds16(gB + (size_t)(j * 8) * KTOT + k0,
                        &sB[wave * 4096 + j * 512]);
        #pragma unroll
        for (int m = 0; m < 4; ++m) {
            a[m][0] = *(const bf16x8*)&p.A[voffA[m][0] + k0];
            a[m][1] = *(const bf16x8*)&p.A[voffA[m][1] + k0];
        }

        __syncthreads();   // vmcnt(0)+lgkmcnt(0) drain + barrier (round-2 exact)

        // ---- MFMA: per wave 64x32 per gate; A regs reused across 4 gates ----
        #pragma unroll
        for (int kk = 0; kk < 2; ++kk) {
            #pragma unroll
            for (int g = 0; g < 4; ++g) {
                #pragma unroll
                for (int n = 0; n < 2; ++n) {
                    bf16x8 b = *(const bf16x8*)&sB[g * 4096 +
                        (wn + n * 16 + lr) * 64 + (kk ? koff1 : koff0)];
                    #pragma unroll
                    for (int m = 0; m < 4; ++m)
                        acc[g][m][n] = __builtin_amdgcn_mfma_f32_16x16x32_bf16(
                            a[m][kk], b, acc[g][m][n], 0, 0, 0);
                }
            }
        }

        __syncthreads();   // protect sB before next stage (round-2 exact)
    }

    // ---- epilogue: bias + ReLU/tanh + cell update ----
    // C/D layout (16x16): col = lane&15, row = (lane>>4)*4 + reg
    float bias[4][2];
    #pragma unroll
    for (int g = 0; g < 4; ++g)
        #pragma unroll
        for (int n = 0; n < 2; ++n)
            bias[g][n] = p.bx[g][bn + wn + n * 16 + lr];

    #pragma unroll
    for (int m = 0; m < 4; ++m) {
        int rbase = bm + wm + m * 16 + (lane >> 4) * 4;
        #pragma unroll
        for (int r = 0; r < 4; ++r) {
            int row = rbase + r;
            #pragma unroll
            for (int n = 0; n < 2; ++n) {
                int col = bn + wn + n * 16 + lr;
                float pf = acc[0][m][n][r] + bias[0][n];
                float pi = acc[1][m][n][r] + bias[1][n];
                float pc = acc[2][m][n][r] + bias[2][n];
                float po = acc[3][m][n][r] + bias[3][n];
                float fg = fmaxf(pf, 0.f);
                float ig = fmaxf(pi, 0.f);
                float og = fmaxf(po, 0.f);
                float ct = fast_tanh(pc);
                float cv = p.c[(size_t)row * HID + col];
                float cn = fg * cv + ig * ct;
                float hn = og * fast_tanh(cn);
                p.oh[(size_t)row * HID + col] = hn;
                p.oc[(size_t)row * HID + col] = cn;
            }
        }
    }
}

// ---------------------------------------------------------------------------
// Fallback (round-1 fused kernel) if d_ws is too small.
// ---------------------------------------------------------------------------
struct Params {
    const float* x; const float* h; const float* c;
    const float* Wx[4]; const float* Wh[4]; const float* bx[4];
    float* oh; float* oc;
};

__global__ __launch_bounds__(256, 2) void relulstm_fallback(Params p) {
    __shared__ short sA[128 * 64];
    __shared__ short sB[4][64 * 64];
    const int t = threadIdx.x;
    const int bm = blockIdx.x * 128;
    const int bn = blockIdx.y * 64;
    const int wave = t >> 6;
    const int lane = t & 63;
    const int wm = (wave >> 1) * 64;
    const int wn = (wave & 1) * 32;
    const int lr = lane & 15;
    const int lk = (lane >> 4) * 8;

    f32x4 acc[4][4][2];
    #pragma unroll
    for (int g = 0; g < 4; ++g)
        #pragma unroll
        for (int m = 0; m < 4; ++m)
            #pragma unroll
            for (int n = 0; n < 2; ++n)
                acc[g][m][n] = (f32x4){0.f, 0.f, 0.f, 0.f};

    for (int k0 = 0; k0 < 2 * HID; k0 += BK) {
        const bool xpart = (k0 < HID);
        const int kb = k0 & (HID - 1);
        const float* __restrict__ srcA = xpart ? p.x : p.h;
        #pragma unroll
        for (int i2 = 0; i2 < 8; ++i2) {
            int cidx = t + i2 * 256;
            int row = cidx >> 4;
            int kc = cidx & 15;
            float4 v = *(const float4*)&srcA[(size_t)(bm + row) * HID + kb + kc * 4];
            int idx = row * BK + ((kc * 4) ^ ((row & 7) << 3));
            short4 s;
            s.x = f2bf(v.x); s.y = f2bf(v.y); s.z = f2bf(v.z); s.w = f2bf(v.w);
            *(short4*)&sA[idx] = s;
        }
        #pragma unroll
        for (int i2 = 0; i2 < 16; ++i2) {
            const int g = i2 >> 2;
            int rem = t + (i2 & 3) * 256;
            int row = rem >> 4;
            int kc = rem & 15;
            const float* __restrict__ srcB = xpart ? p.Wx[g] : p.Wh[g];
            float4 v = *(const float4*)&srcB[(size_t)(bn + row) * HID + kb + kc * 4];
            int idx = row * BK + ((kc * 4) ^ ((row & 7) << 3));
            short4 s;
            s.x = f2bf(v.x); s.y = f2bf(v.y); s.z = f2bf(v.z); s.w = f2bf(v.w);
            *(short4*)&sB[g][idx] = s;
        }
        __syncthreads();
        #pragma unroll
        for (int kk = 0; kk < 2; ++kk) {
            bf16x8 a[4];
            #pragma unroll
            for (int m = 0; m < 4; ++m) {
                int row = wm + m * 16 + lr;
                int kidx = (kk * 32 + lk) ^ ((row & 7) << 3);
                a[m] = *(const bf16x8*)&sA[row * BK + kidx];
            }
            #pragma unroll
            for (int g = 0; g < 4; ++g) {
                #pragma unroll
                for (int n = 0; n < 2; ++n) {
                    int brow = wn + n * 16 + lr;
                    int kidx = (kk * 32 + lk) ^ ((brow & 7) << 3);
                    bf16x8 b = *(const bf16x8*)&sB[g][brow * BK + kidx];
                    #pragma unroll
                    for (int m = 0; m < 4; ++m)
                        acc[g][m][n] = __builtin_amdgcn_mfma_f32_16x16x32_bf16(
                            a[m], b, acc[g][m][n], 0, 0, 0);
                }
            }
        }
        __syncthreads();
    }

    float bias[4][2];
    #pragma unroll
    for (int g = 0; g < 4; ++g)
        #pragma unroll
        for (int n = 0; n < 2; ++n)
            bias[g][n] = p.bx[g][bn + wn + n * 16 + lr];

    #pragma unroll
    for (int m = 0; m < 4; ++m) {
        int rbase = bm + wm + m * 16 + (lane >> 4) * 4;
        #pragma unroll
        for (int r = 0; r < 4; ++r) {
            int row = rbase + r;
            #pragma unroll
            for (int n = 0; n < 2; ++n) {
                int col = bn + wn + n * 16 + lr;
                float pf = acc[0][m][n][r] + bias[0][n];
                float pi = acc[1][m][n][r] + bias[1][n];
                float pc = acc[2][m][n][r] + bias[2][n];
                float po = acc[3][m][n][r] + bias[3][n];
                float fg = fmaxf(pf, 0.f);
                float ig = fmaxf(pi, 0.f);
                float og = fmaxf(po, 0.f);
                float ct = fast_tanh(pc);
                float cv = p.c[(size_t)row * HID + col];
                float cn = fg * cv + ig * ct;
                float hn = og * fast_tanh(cn);
                p.oh[(size_t)row * HID + col] = hn;
                p.oc[(size_t)row * HID + col] = cn;
            }
        }
    }
}

extern "C" void kernel_launch(void* const* d_in, const int* in_sizes, int n_in,
                              void* d_out, int out_size, void* d_ws, size_t ws_size,
                              hipStream_t stream) {
    (void)in_sizes; (void)n_in; (void)out_size;
    const size_t A_BYTES = (size_t)BATCH_N * KTOT * 2;
    const size_t B_BYTES = (size_t)4 * HID * KTOT * 2;

    if (ws_size >= A_BYTES + B_BYTES) {
        short* A = (short*)d_ws;
        short* B = A + (size_t)BATCH_N * KTOT;

        CastParams q;
        q.x = (const float*)d_in[0];
        q.h = (const float*)d_in[1];
        for (int g = 0; g < 4; ++g) {
            q.Wx[g] = (const float*)d_in[3 + 3 * g];
            q.Wh[g] = (const float*)d_in[5 + 3 * g];
        }
        q.A = A; q.B = B;
        precast_kernel<<<2048, 256, 0, stream>>>(q);

        GemmParams p;
        p.A = A; p.B = B;
        p.c = (const float*)d_in[2];
        for (int g = 0; g < 4; ++g) p.bx[g] = (const float*)d_in[4 + 3 * g];
        p.oh = (float*)d_out;
        p.oc = (float*)d_out + (size_t)BATCH_N * HID;
        gemm_lstm_adir2<<<dim3(1024), THREADS, 0, stream>>>(p);
    } else {
        Params p;
        p.x = (const float*)d_in[0];
        p.h = (const float*)d_in[1];
        p.c = (const float*)d_in[2];
        for (int g = 0; g < 4; ++g) {
            p.Wx[g] = (const float*)d_in[3 + 3 * g];
            p.bx[g] = (const float*)d_in[4 + 3 * g];
            p.Wh[g] = (const float*)d_in[5 + 3 * g];
        }
        p.oh = (float*)d_out;
        p.oc = (float*)d_out + (size_t)BATCH_N * HID;
        dim3 grid(BATCH_N / 128, HID / 64);
        relulstm_fallback<<<grid, 256, 0, stream>>>(p);
    }
}

// Round 8
// 319.369 us; speedup vs baseline: 1.1626x; 1.1626x over previous
//
#include <hip/hip_runtime.h>
#include <hip/hip_bf16.h>

// ReLU-LSTM fused (final stable config = round-2 structure): precast
// f32->bf16 (pre-swizzled) into d_ws, then m97-style global_load_lds GEMM
// with 4-gate shared-A accumulation and in-register LSTM epilogue.
// Measured: GEMM 284 us (968 TF, MfmaUtil 44.6%, 0 bank conflicts),
// precast ~34 us; total 318 us. Schedule variants measured and rejected:
// 8-phase counted-vmcnt (282), 32x32x16 MFMA (314, 4-way LDS conflicts),
// register read-ahead (297), B-dbuf ping-pong (raced post-timing),
// A-direct-from-global (323, FETCH 2x).

#define HID 2048
#define BATCH_N 4096
#define KTOT 4096          // K = 2*HID ([x|h] concat)
#define BM 128
#define BN 64              // per gate
#define BK 64
#define THREADS 256

typedef __attribute__((ext_vector_type(4))) float f32x4;
typedef __attribute__((ext_vector_type(8))) short bf16x8;

__device__ __forceinline__ short f2bf(float f) {
    union { float f; unsigned u; } v; v.f = f;
    unsigned r = v.u + 0x7FFFu + ((v.u >> 16) & 1u);
    return (short)(r >> 16);
}

__device__ __forceinline__ float fast_tanh(float v) {
    float e = __expf(2.0f * v);
    return 1.0f - 2.0f / (e + 1.0f);
}

__device__ __forceinline__ void gload_lds16(const short* g, short* l) {
    __builtin_amdgcn_global_load_lds(
        (const __attribute__((address_space(1))) unsigned int*)g,
        (__attribute__((address_space(3))) unsigned int*)l, 16, 0, 0);
}

// ---------------------------------------------------------------------------
// Kernel 1: precast f32 -> bf16 with within-64 K-swizzle keyed on (row&7).
// Stored col = (k & ~63) | ((k&63) ^ ((row&7)<<3)) so that a LINEAR
// global_load_lds stage yields a swizzled LDS tile (rule 21).
// ---------------------------------------------------------------------------
struct CastParams {
    const float* x; const float* h;
    const float* Wx[4]; const float* Wh[4];
    short* A; short* B;
};

__global__ __launch_bounds__(256) void precast_kernel(CastParams q) {
    const long A_CH = (long)BATCH_N * (KTOT / 8);   // 2^21 16B-chunks
    const long B_CH = 4L * HID * (KTOT / 8);        // 2^22
    const long total = A_CH + B_CH;
    for (long idx = (long)blockIdx.x * 256 + threadIdx.x; idx < total;
         idx += (long)gridDim.x * 256) {
        const float* src; short* dst; int row, k;
        if (idx < A_CH) {
            row = (int)(idx >> 9);
            k = (int)(idx & 511) << 3;
            src = (k < HID) ? &q.x[(size_t)row * HID + k]
                            : &q.h[(size_t)row * HID + (k - HID)];
            dst = &q.A[(size_t)row * KTOT];
        } else {
            long r = idx - A_CH;
            int g = (int)(r >> 20);                 // 2048*512 = 2^20 per gate
            int rem = (int)(r & ((1 << 20) - 1));
            row = rem >> 9;
            k = (rem & 511) << 3;
            src = (k < HID) ? &q.Wx[g][(size_t)row * HID + k]
                            : &q.Wh[g][(size_t)row * HID + (k - HID)];
            dst = &q.B[((size_t)g * HID + row) * KTOT];
        }
        float4 v0 = *(const float4*)src;
        float4 v1 = *(const float4*)(src + 4);
        int col = (k & ~63) | ((k & 63) ^ ((row & 7) << 3));
        bf16x8 s;
        s[0] = f2bf(v0.x); s[1] = f2bf(v0.y); s[2] = f2bf(v0.z); s[3] = f2bf(v0.w);
        s[4] = f2bf(v1.x); s[5] = f2bf(v1.y); s[6] = f2bf(v1.z); s[7] = f2bf(v1.w);
        *(bf16x8*)&dst[col] = s;
    }
}

// ---------------------------------------------------------------------------
// Kernel 2: fused 4-gate GEMM + LSTM epilogue, m97 structure.
// Block: 128 (batch) x 64 (hidden) x all 4 gates. 4 waves, 2x2.
// Staging: global_load_lds width 16, linear LDS dest; ds_read applies swizzle.
// ---------------------------------------------------------------------------
struct GemmParams {
    const short* A; const short* B;
    const float* bx[4];
    const float* c;
    float* oh; float* oc;
};

__global__ __launch_bounds__(THREADS, 2) void gemm_lstm_kernel(GemmParams p) {
    __shared__ short sA[BM * BK];        // 16 KB
    __shared__ short sB[4 * BN * BK];    // 32 KB

    const int t = threadIdx.x;
    const int bm = blockIdx.x * BM;
    const int bn = blockIdx.y * BN;
    const int wave = t >> 6;
    const int lane = t & 63;
    const int wm = (wave >> 1) * 64;
    const int wn = (wave & 1) * 32;
    const int lr = lane & 15;
    const int lk = (lane >> 4) * 8;

    f32x4 acc[4][4][2];
    #pragma unroll
    for (int g = 0; g < 4; ++g)
        #pragma unroll
        for (int m = 0; m < 4; ++m)
            #pragma unroll
            for (int n = 0; n < 2; ++n)
                acc[g][m][n] = (f32x4){0.f, 0.f, 0.f, 0.f};

    // staging geometry: per global_load_lds call a wave covers 8 rows x 64 k
    const int srow = lane >> 3;              // row within 8-row group
    const int kch = (lane & 7) * 8;          // k-chunk (elements)
    const short* gA = p.A + (size_t)(bm + wave * 32 + srow) * KTOT + kch;
    // B: wave w stages gate w; n = j*8 + srow
    const short* gB = p.B + ((size_t)wave * HID + bn + srow) * KTOT + kch;

    for (int k0 = 0; k0 < KTOT; k0 += BK) {
        #pragma unroll
        for (int j = 0; j < 4; ++j)
            gload_lds16(gA + (size_t)(j * 8) * KTOT + k0,
                        &sA[(wave * 32 + j * 8) * BK]);
        #pragma unroll
        for (int j = 0; j < 8; ++j)
            gload_lds16(gB + (size_t)(j * 8) * KTOT + k0,
                        &sB[(wave * 64 + j * 8) * BK]);

        __syncthreads();

        #pragma unroll
        for (int kk = 0; kk < 2; ++kk) {
            bf16x8 a[4];
            #pragma unroll
            for (int m = 0; m < 4; ++m) {
                int row = wm + m * 16 + lr;
                int kidx = (kk * 32 + lk) ^ ((row & 7) << 3);
                a[m] = *(const bf16x8*)&sA[row * BK + kidx];
            }
            #pragma unroll
            for (int g = 0; g < 4; ++g) {
                #pragma unroll
                for (int n = 0; n < 2; ++n) {
                    int brow = wn + n * 16 + lr;
                    int kidx = (kk * 32 + lk) ^ ((brow & 7) << 3);
                    bf16x8 b = *(const bf16x8*)&sB[(g * BN + brow) * BK + kidx];
                    #pragma unroll
                    for (int m = 0; m < 4; ++m)
                        acc[g][m][n] = __builtin_amdgcn_mfma_f32_16x16x32_bf16(
                            a[m], b, acc[g][m][n], 0, 0, 0);
                }
            }
        }

        __syncthreads();
    }

    // epilogue: bias + ReLU/tanh + cell update (C/D: col=lane&15, row=(lane>>4)*4+r)
    float bias[4][2];
    #pragma unroll
    for (int g = 0; g < 4; ++g)
        #pragma unroll
        for (int n = 0; n < 2; ++n)
            bias[g][n] = p.bx[g][bn + wn + n * 16 + lr];

    #pragma unroll
    for (int m = 0; m < 4; ++m) {
        int rbase = bm + wm + m * 16 + (lane >> 4) * 4;
        #pragma unroll
        for (int r = 0; r < 4; ++r) {
            int row = rbase + r;
            #pragma unroll
            for (int n = 0; n < 2; ++n) {
                int col = bn + wn + n * 16 + lr;
                float pf = acc[0][m][n][r] + bias[0][n];
                float pi = acc[1][m][n][r] + bias[1][n];
                float pc = acc[2][m][n][r] + bias[2][n];
                float po = acc[3][m][n][r] + bias[3][n];
                float fg = fmaxf(pf, 0.f);
                float ig = fmaxf(pi, 0.f);
                float og = fmaxf(po, 0.f);
                float ct = fast_tanh(pc);
                float cv = p.c[(size_t)row * HID + col];
                float cn = fg * cv + ig * ct;
                float hn = og * fast_tanh(cn);
                p.oh[(size_t)row * HID + col] = hn;
                p.oc[(size_t)row * HID + col] = cn;
            }
        }
    }
}

// ---------------------------------------------------------------------------
// Fallback (round-1 fused kernel, f32 in-loop cast) if d_ws is too small.
// ---------------------------------------------------------------------------
struct Params {
    const float* x; const float* h; const float* c;
    const float* Wx[4]; const float* Wh[4]; const float* bx[4];
    float* oh; float* oc;
};

__global__ __launch_bounds__(THREADS, 2) void relulstm_fallback(Params p) {
    __shared__ short sA[BM * BK];
    __shared__ short sB[4][BN * BK];
    const int t = threadIdx.x;
    const int bm = blockIdx.x * BM;
    const int bn = blockIdx.y * BN;
    const int wave = t >> 6;
    const int lane = t & 63;
    const int wm = (wave >> 1) * 64;
    const int wn = (wave & 1) * 32;
    const int lr = lane & 15;
    const int lk = (lane >> 4) * 8;

    f32x4 acc[4][4][2];
    #pragma unroll
    for (int g = 0; g < 4; ++g)
        #pragma unroll
        for (int m = 0; m < 4; ++m)
            #pragma unroll
            for (int n = 0; n < 2; ++n)
                acc[g][m][n] = (f32x4){0.f, 0.f, 0.f, 0.f};

    for (int k0 = 0; k0 < 2 * HID; k0 += BK) {
        const bool xpart = (k0 < HID);
        const int kb = k0 & (HID - 1);
        const float* __restrict__ srcA = xpart ? p.x : p.h;
        #pragma unroll
        for (int i2 = 0; i2 < 8; ++i2) {
            int cidx = t + i2 * THREADS;
            int row = cidx >> 4;
            int kc = cidx & 15;
            float4 v = *(const float4*)&srcA[(size_t)(bm + row) * HID + kb + kc * 4];
            int idx = row * BK + ((kc * 4) ^ ((row & 7) << 3));
            short4 s;
            s.x = f2bf(v.x); s.y = f2bf(v.y); s.z = f2bf(v.z); s.w = f2bf(v.w);
            *(short4*)&sA[idx] = s;
        }
        #pragma unroll
        for (int i2 = 0; i2 < 16; ++i2) {
            const int g = i2 >> 2;
            int rem = t + (i2 & 3) * THREADS;
            int row = rem >> 4;
            int kc = rem & 15;
            const float* __restrict__ srcB = xpart ? p.Wx[g] : p.Wh[g];
            float4 v = *(const float4*)&srcB[(size_t)(bn + row) * HID + kb + kc * 4];
            int idx = row * BK + ((kc * 4) ^ ((row & 7) << 3));
            short4 s;
            s.x = f2bf(v.x); s.y = f2bf(v.y); s.z = f2bf(v.z); s.w = f2bf(v.w);
            *(short4*)&sB[g][idx] = s;
        }
        __syncthreads();
        #pragma unroll
        for (int kk = 0; kk < 2; ++kk) {
            bf16x8 a[4];
            #pragma unroll
            for (int m = 0; m < 4; ++m) {
                int row = wm + m * 16 + lr;
                int kidx = (kk * 32 + lk) ^ ((row & 7) << 3);
                a[m] = *(const bf16x8*)&sA[row * BK + kidx];
            }
            #pragma unroll
            for (int g = 0; g < 4; ++g) {
                #pragma unroll
                for (int n = 0; n < 2; ++n) {
                    int brow = wn + n * 16 + lr;
                    int kidx = (kk * 32 + lk) ^ ((brow & 7) << 3);
                    bf16x8 b = *(const bf16x8*)&sB[g][brow * BK + kidx];
                    #pragma unroll
                    for (int m = 0; m < 4; ++m)
                        acc[g][m][n] = __builtin_amdgcn_mfma_f32_16x16x32_bf16(
                            a[m], b, acc[g][m][n], 0, 0, 0);
                }
            }
        }
        __syncthreads();
    }

    float bias[4][2];
    #pragma unroll
    for (int g = 0; g < 4; ++g)
        #pragma unroll
        for (int n = 0; n < 2; ++n)
            bias[g][n] = p.bx[g][bn + wn + n * 16 + lr];

    #pragma unroll
    for (int m = 0; m < 4; ++m) {
        int rbase = bm + wm + m * 16 + (lane >> 4) * 4;
        #pragma unroll
        for (int r = 0; r < 4; ++r) {
            int row = rbase + r;
            #pragma unroll
            for (int n = 0; n < 2; ++n) {
                int col = bn + wn + n * 16 + lr;
                float pf = acc[0][m][n][r] + bias[0][n];
                float pi = acc[1][m][n][r] + bias[1][n];
                float pc = acc[2][m][n][r] + bias[2][n];
                float po = acc[3][m][n][r] + bias[3][n];
                float fg = fmaxf(pf, 0.f);
                float ig = fmaxf(pi, 0.f);
                float og = fmaxf(po, 0.f);
                float ct = fast_tanh(pc);
                float cv = p.c[(size_t)row * HID + col];
                float cn = fg * cv + ig * ct;
                float hn = og * fast_tanh(cn);
                p.oh[(size_t)row * HID + col] = hn;
                p.oc[(size_t)row * HID + col] = cn;
            }
        }
    }
}

extern "C" void kernel_launch(void* const* d_in, const int* in_sizes, int n_in,
                              void* d_out, int out_size, void* d_ws, size_t ws_size,
                              hipStream_t stream) {
    (void)in_sizes; (void)n_in; (void)out_size;
    const size_t A_BYTES = (size_t)BATCH_N * KTOT * 2;        // 33.5 MB
    const size_t B_BYTES = (size_t)4 * HID * KTOT * 2;        // 67.1 MB

    if (ws_size >= A_BYTES + B_BYTES) {
        short* A = (short*)d_ws;
        short* B = A + (size_t)BATCH_N * KTOT;

        CastParams q;
        q.x = (const float*)d_in[0];
        q.h = (const float*)d_in[1];
        for (int g = 0; g < 4; ++g) {
            q.Wx[g] = (const float*)d_in[3 + 3 * g];
            q.Wh[g] = (const float*)d_in[5 + 3 * g];
        }
        q.A = A; q.B = B;
        precast_kernel<<<2048, 256, 0, stream>>>(q);

        GemmParams p;
        p.A = A; p.B = B;
        p.c = (const float*)d_in[2];
        for (int g = 0; g < 4; ++g) p.bx[g] = (const float*)d_in[4 + 3 * g];
        p.oh = (float*)d_out;
        p.oc = (float*)d_out + (size_t)BATCH_N * HID;
        dim3 grid(BATCH_N / BM, HID / BN);    // 32 x 32
        gemm_lstm_kernel<<<grid, THREADS, 0, stream>>>(p);
    } else {
        Params p;
        p.x = (const float*)d_in[0];
        p.h = (const float*)d_in[1];
        p.c = (const float*)d_in[2];
        for (int g = 0; g < 4; ++g) {
            p.Wx[g] = (const float*)d_in[3 + 3 * g];
            p.bx[g] = (const float*)d_in[4 + 3 * g];
            p.Wh[g] = (const float*)d_in[5 + 3 * g];
        }
        p.oh = (float*)d_out;
        p.oc = (float*)d_out + (size_t)BATCH_N * HID;
        dim3 grid(BATCH_N / BM, HID / BN);
        relulstm_fallback<<<grid, THREADS, 0, stream>>>(p);
    }
}